// Round 18
// baseline (149.339 us; speedup 1.0000x reference)
//
#include <hip/hip_runtime.h>
#include <hip/hip_bf16.h>

#define BB 4
#define LL 2048
#define KK 48
#define HH 128
#define CANDCAP 384
#define FSTR 40              // feat row stride (shorts)
#define DLT 1.06666666667f   // (4/3)*0.8
#define BINSCALE 2.0f        // linear d2 binning: 0.5 A^2 buckets

using bf16x8 = __attribute__((ext_vector_type(8))) short;
using f32x4  = __attribute__((ext_vector_type(4))) float;
using u64x2  = __attribute__((ext_vector_type(2))) unsigned long long;

// ---- prep 1: Wt fragment layout, 16 K-steps (13 rbf + 3 pe one-hot) --------
__global__ __launch_bounds__(256) void pf18_prep_w(
    const float* __restrict__ Wedge, const float* __restrict__ Wpos,
    const float* __restrict__ bpos, short* __restrict__ Wt) {
    int idx = blockIdx.x * 256 + threadIdx.x;          // 16*8*16*32 = 65536
    if (idx >= 16 * 8 * 16 * 32) return;
    int j  = idx & 7;
    int kg = (idx >> 3) & 3;
    int col = (idx >> 5) & 15;
    int nt = (idx >> 9) & 7;
    int kt = idx >> 12;
    int k = kt * 32 + kg * 8 + j;
    int n = nt * 16 + col;
    float v = 0.0f;
    if (kt < 13) {
        if (k < 400) v = Wedge[(size_t)(16 + k) * HH + n];
    } else {
        int d = k - 416;
        if (d < 66) {
            float s = 0.f;
            #pragma unroll
            for (int p = 0; p < 16; ++p)
                s += (Wpos[d * 16 + p] + bpos[p]) * Wedge[p * HH + n];
            v = s;
        }
    }
    __hip_bfloat16 h = __float2bfloat16(v);
    Wt[idx] = *reinterpret_cast<short*>(&h);
}

// ---- prep 2: packed CA + mask-bias table -----------------------------------
__global__ __launch_bounds__(256) void pf18_prep_ca(const float* __restrict__ X,
                                                    const float* __restrict__ mask,
                                                    float4* __restrict__ caq) {
    int i = blockIdx.x * 256 + threadIdx.x;            // B*L = 8192
    if (i >= BB * LL) return;
    const float* x = X + (size_t)i * 12;
    float bias = __fmul_rn(1.0f - mask[i], 1.0e6f);
    caq[i] = make_float4(x[3], x[4], x[5], bias);
}

// ---- main ------------------------------------------------------------------
__global__ __launch_bounds__(256, 6) void pf18_main(
    const float* __restrict__ X,
    const int* __restrict__ Ridx, const int* __restrict__ chain,
    const float* __restrict__ gamma, const float* __restrict__ beta,
    const short* __restrict__ Wt, const float4* __restrict__ caq,
    float* __restrict__ outIdx, float* __restrict__ outEdge) {

    const int row = blockIdx.x;             // b*L + l
    const int bq = row >> 11, lq = row & (LL - 1);
    const int tid = threadIdx.x;
    const int lane = tid & 63, wid = tid >> 6;
    const float* Xb = X + (size_t)bq * LL * 12;
    const float4* caqb = caq + (size_t)bq * LL;

    __shared__ __align__(16) union {
        int hist[1024];
        unsigned long long cand[CANDCAP];
        float geo[KK * 15 + 16];             // nb[48][15] + self @720
    } uA;
    __shared__ float sD[KK * 25];
    __shared__ __align__(16) short sFeat[4][KK * FSTR];   // quad-buffered
    __shared__ float sGB[2 * HH];
    __shared__ float sPartS[KK][4], sPartSS[KK][4];
    __shared__ float sMean[KK], sInv[KK];
    __shared__ int sSel[KK], sDcode[KK];
    __shared__ int sWsum[4];
    __shared__ int sBstar, sCc;

    if (tid < HH) { sGB[tid * 2] = gamma[tid]; sGB[tid * 2 + 1] = beta[tid]; }

    // ------------------------------------------------ top-k: distances ----
    const float4 sc = caqb[lq];
    float dval[8];
    #pragma unroll
    for (int i = 0; i < 8; ++i) {
        float4 q = caqb[i * 256 + tid];
        float dx = __fadd_rn(sc.x, -q.x);
        float dy = __fadd_rn(sc.y, -q.y);
        float dz = __fadd_rn(sc.z, -q.z);
        float d2 = __fadd_rn(__fadd_rn(__fmul_rn(dx, dx), __fmul_rn(dy, dy)),
                             __fmul_rn(dz, dz));
        dval[i] = __fadd_rn(d2, q.w);
    }

    *reinterpret_cast<int4*>(&uA.hist[tid * 4]) = make_int4(0, 0, 0, 0);
    if (tid == 0) sCc = 0;
    __syncthreads();                                    // B1
    #pragma unroll
    for (int i = 0; i < 8; ++i) {
        int bin = (int)(dval[i] * BINSCALE);
        bin = bin > 1023 ? 1023 : bin;
        atomicAdd(&uA.hist[bin], 1);
    }
    __syncthreads();                                    // B2

    int c0 = uA.hist[tid * 4 + 0];
    int c1 = uA.hist[tid * 4 + 1];
    int c2 = uA.hist[tid * 4 + 2];
    int c3 = uA.hist[tid * 4 + 3];
    int local = c0 + c1 + c2 + c3;
    int v = local;
    #pragma unroll
    for (int off = 1; off < 64; off <<= 1) {
        int o = __shfl_up(v, off, 64);
        if (lane >= off) v += o;
    }
    if (lane == 63) sWsum[wid] = v;
    __syncthreads();                                    // B3
    int woff = 0;
    #pragma unroll
    for (int w2 = 0; w2 < 4; ++w2) if (w2 < wid) woff += sWsum[w2];
    int incl = woff + v, excl = incl - local;
    if (excl < KK && incl >= KK) {
        int cum = excl, b = tid * 4;
        if (cum + c0 >= KK) sBstar = b;
        else { cum += c0;
            if (cum + c1 >= KK) sBstar = b + 1;
            else { cum += c1;
                if (cum + c2 >= KK) sBstar = b + 2;
                else sBstar = b + 3; } }
    }
    __syncthreads();                                    // B4 (hist dead)

    int bstar = sBstar;
    #pragma unroll
    for (int i = 0; i < 8; ++i) {
        int bin = (int)(dval[i] * BINSCALE);
        bin = bin > 1023 ? 1023 : bin;
        if (bin <= bstar) {
            int pos = atomicAdd(&sCc, 1);
            if (pos < CANDCAP)
                uA.cand[pos] =
                    ((unsigned long long)__float_as_uint(dval[i]) << 32)
                    | (unsigned)(i * 256 + tid);
        }
    }
    __syncthreads();                                    // B5

    // exact rank, vectorized candidate scan (ties -> lower index)
    int C = sCc < CANDCAP ? sCc : CANDCAP;
    for (int ci = tid; ci < C; ci += 256) {
        unsigned long long me = uA.cand[ci];
        int rank = 0, j2 = 0;
        int Cv = C & ~7;
        for (; j2 < Cv; j2 += 8) {
            u64x2 q0 = *reinterpret_cast<u64x2*>(&uA.cand[j2]);
            u64x2 q1 = *reinterpret_cast<u64x2*>(&uA.cand[j2 + 2]);
            u64x2 q2 = *reinterpret_cast<u64x2*>(&uA.cand[j2 + 4]);
            u64x2 q3 = *reinterpret_cast<u64x2*>(&uA.cand[j2 + 6]);
            rank += (q0[0] < me) + (q0[1] < me) + (q1[0] < me) + (q1[1] < me)
                  + (q2[0] < me) + (q2[1] < me) + (q3[0] < me) + (q3[1] < me);
        }
        for (; j2 < C; ++j2) rank += (uA.cand[j2] < me) ? 1 : 0;
        if (rank < KK) sSel[rank] = (int)(me & 0xFFFFFFFFu);
    }
    __syncthreads();                                    // B6 (cand dead)

    if (tid < KK) outIdx[(size_t)row * KK + tid] = (float)sSel[tid];

    // --------------------------------- neighbor atoms (with CB) + dcode ----
    const float KA = -0.58273431f, KB2 = 0.56802827f, KC = -0.54067466f;
    if (tid < KK) {
        int j = sSel[tid];
        const float* x = Xb + (size_t)j * 12;
        float u0 = x[3] - x[0], u1 = x[4] - x[1], u2 = x[5] - x[2];
        float w0 = x[6] - x[3], w1 = x[7] - x[4], w2 = x[8] - x[5];
        float r0 = u1 * w2 - u2 * w1;
        float r1 = u2 * w0 - u0 * w2;
        float r2 = u0 * w1 - u1 * w0;
        float* o = &uA.geo[tid * 15];
        #pragma unroll
        for (int t = 0; t < 12; ++t) o[t] = x[t];
        o[12] = KA * r0 + KB2 * u0 + KC * w0 + x[3];
        o[13] = KA * r1 + KB2 * u1 + KC * w1 + x[4];
        o[14] = KA * r2 + KB2 * u2 + KC * w2 + x[5];
        int offr = Ridx[row] - Ridx[(size_t)bq * LL + j];
        int same = (chain[row] == chain[(size_t)bq * LL + j]);
        int d = offr + 32;
        d = d < 0 ? 0 : (d > 64 ? 64 : d);
        sDcode[tid] = same ? d : 65;
    }
    if (tid == 64) {
        const float* x = Xb + (size_t)lq * 12;
        float u0 = x[3] - x[0], u1 = x[4] - x[1], u2 = x[5] - x[2];
        float w0 = x[6] - x[3], w1 = x[7] - x[4], w2 = x[8] - x[5];
        float r0 = u1 * w2 - u2 * w1;
        float r1 = u2 * w0 - u0 * w2;
        float r2 = u0 * w1 - u1 * w0;
        float* s = &uA.geo[720];
        #pragma unroll
        for (int t = 0; t < 12; ++t) s[t] = x[t];
        s[12] = KA * r0 + KB2 * u0 + KC * w0 + x[3];
        s[13] = KA * r1 + KB2 * u1 + KC * w1 + x[4];
        s[14] = KA * r2 + KB2 * u2 + KC * w2 + x[5];
    }
    __syncthreads();                                    // B7

    // ---------------------- pairwise distances (no integer division) --------
    #pragma unroll
    for (int it = 0; it < 6; ++it) {
        int idx = it * 256 + tid;
        int k = idx >> 5, pq = idx & 31;
        if (pq < 25) {
            int p = pq / 5, q = pq % 5;
            float dx = uA.geo[720 + p * 3 + 0] - uA.geo[k * 15 + q * 3 + 0];
            float dy = uA.geo[720 + p * 3 + 1] - uA.geo[k * 15 + q * 3 + 1];
            float dz = uA.geo[720 + p * 3 + 2] - uA.geo[k * 15 + q * 3 + 2];
            sD[k * 25 + pq] = sqrtf(dx * dx + dy * dy + dz * dz + 1e-6f);
        }
    }
    __syncthreads();                                    // B8

    // ------------------------------------- feature compute (one K-step) ----
    auto feat_compute = [&](int kt, int fb) {
        if (tid < 192) {
            int pair = tid >> 1, half = tid & 1;
            int k = pair >> 1, pq_lo = pair & 1;
            int pq = kt * 2 + pq_lo;
            bf16x8 ov;
            if (pq < 25) {
                float Dv = sD[k * 25 + pq];
                float t0 = (Dv - 2.0f) * 0.8f;
                float tm = __builtin_fmaf(-(float)(half << 3), DLT, t0);
                #pragma unroll
                for (int mi = 0; mi < 8; ++mi) {
                    float val = __expf(-tm * tm);
                    __hip_bfloat16 hb = __float2bfloat16(val);
                    ov[mi] = *reinterpret_cast<short*>(&hb);
                    tm -= DLT;
                }
            } else {
                #pragma unroll
                for (int mi = 0; mi < 8; ++mi) ov[mi] = 0;
            }
            *reinterpret_cast<bf16x8*>(
                &sFeat[fb][k * FSTR + pq_lo * 16 + (half << 3)]) = ov;
        }
    };

    // prologue: fill buffers 0 and 1 (K-steps 0,1)
    feat_compute(0, 0);
    feat_compute(1, 1);
    __syncthreads();                                    // B9

    // ---------------- MFMA GEMM: 6 double-K iterations + K-step-12 tail -----
    f32x4 acc[3][2];
    #pragma unroll
    for (int mt = 0; mt < 3; ++mt)
        #pragma unroll
        for (int nb = 0; nb < 2; ++nb) acc[mt][nb] = (f32x4){0.f, 0.f, 0.f, 0.f};
    const int nt0 = wid * 2;
    const int arow = lane & 15, kg = lane >> 4;
    const short* wpBase = Wt + (((size_t)nt0 * 16 + arow) * 32 + kg * 8);
    const int K32S = 8 * 16 * 32;                       // shorts per K32-step

    #pragma unroll 1
    for (int kt = 0; kt < 12; kt += 2) {
        const short* wpA = wpBase + (size_t)kt * K32S;
        bf16x8 bA0 = *reinterpret_cast<const bf16x8*>(wpA);
        bf16x8 bA1 = *reinterpret_cast<const bf16x8*>(wpA + 16 * 32);
        bf16x8 bB0 = *reinterpret_cast<const bf16x8*>(wpA + K32S);
        bf16x8 bB1 = *reinterpret_cast<const bf16x8*>(wpA + K32S + 16 * 32);
        // produce the next two buffers while consuming current two
        feat_compute(kt + 2, (kt + 2) & 3);
        if (kt + 3 < 13) feat_compute(kt + 3, (kt + 3) & 3);
        const short* fA = &sFeat[kt & 3][0];
        const short* fB = &sFeat[(kt + 1) & 3][0];
        bf16x8 a0 = *reinterpret_cast<const bf16x8*>(&fA[(arow     ) * FSTR + kg * 8]);
        bf16x8 a1 = *reinterpret_cast<const bf16x8*>(&fA[(arow + 16) * FSTR + kg * 8]);
        bf16x8 a2 = *reinterpret_cast<const bf16x8*>(&fA[(arow + 32) * FSTR + kg * 8]);
        acc[0][0] = __builtin_amdgcn_mfma_f32_16x16x32_bf16(a0, bA0, acc[0][0], 0, 0, 0);
        acc[1][0] = __builtin_amdgcn_mfma_f32_16x16x32_bf16(a1, bA0, acc[1][0], 0, 0, 0);
        acc[2][0] = __builtin_amdgcn_mfma_f32_16x16x32_bf16(a2, bA0, acc[2][0], 0, 0, 0);
        acc[0][1] = __builtin_amdgcn_mfma_f32_16x16x32_bf16(a0, bA1, acc[0][1], 0, 0, 0);
        acc[1][1] = __builtin_amdgcn_mfma_f32_16x16x32_bf16(a1, bA1, acc[1][1], 0, 0, 0);
        acc[2][1] = __builtin_amdgcn_mfma_f32_16x16x32_bf16(a2, bA1, acc[2][1], 0, 0, 0);
        bf16x8 a3 = *reinterpret_cast<const bf16x8*>(&fB[(arow     ) * FSTR + kg * 8]);
        bf16x8 a4 = *reinterpret_cast<const bf16x8*>(&fB[(arow + 16) * FSTR + kg * 8]);
        bf16x8 a5 = *reinterpret_cast<const bf16x8*>(&fB[(arow + 32) * FSTR + kg * 8]);
        acc[0][0] = __builtin_amdgcn_mfma_f32_16x16x32_bf16(a3, bB0, acc[0][0], 0, 0, 0);
        acc[1][0] = __builtin_amdgcn_mfma_f32_16x16x32_bf16(a4, bB0, acc[1][0], 0, 0, 0);
        acc[2][0] = __builtin_amdgcn_mfma_f32_16x16x32_bf16(a5, bB0, acc[2][0], 0, 0, 0);
        acc[0][1] = __builtin_amdgcn_mfma_f32_16x16x32_bf16(a3, bB1, acc[0][1], 0, 0, 0);
        acc[1][1] = __builtin_amdgcn_mfma_f32_16x16x32_bf16(a4, bB1, acc[1][1], 0, 0, 0);
        acc[2][1] = __builtin_amdgcn_mfma_f32_16x16x32_bf16(a5, bB1, acc[2][1], 0, 0, 0);
        __syncthreads();                                // B10..B15 (6 total)
    }

    // tail: K-step 12 (buffer 12&3 = 0, published by the kt=10 iteration)
    {
        const short* wp = wpBase + (size_t)12 * K32S;
        bf16x8 b0 = *reinterpret_cast<const bf16x8*>(wp);
        bf16x8 b1 = *reinterpret_cast<const bf16x8*>(wp + 16 * 32);
        const short* fA = &sFeat[0][0];
        bf16x8 a0 = *reinterpret_cast<const bf16x8*>(&fA[(arow     ) * FSTR + kg * 8]);
        bf16x8 a1 = *reinterpret_cast<const bf16x8*>(&fA[(arow + 16) * FSTR + kg * 8]);
        bf16x8 a2 = *reinterpret_cast<const bf16x8*>(&fA[(arow + 32) * FSTR + kg * 8]);
        acc[0][0] = __builtin_amdgcn_mfma_f32_16x16x32_bf16(a0, b0, acc[0][0], 0, 0, 0);
        acc[1][0] = __builtin_amdgcn_mfma_f32_16x16x32_bf16(a1, b0, acc[1][0], 0, 0, 0);
        acc[2][0] = __builtin_amdgcn_mfma_f32_16x16x32_bf16(a2, b0, acc[2][0], 0, 0, 0);
        acc[0][1] = __builtin_amdgcn_mfma_f32_16x16x32_bf16(a0, b1, acc[0][1], 0, 0, 0);
        acc[1][1] = __builtin_amdgcn_mfma_f32_16x16x32_bf16(a1, b1, acc[1][1], 0, 0, 0);
        acc[2][1] = __builtin_amdgcn_mfma_f32_16x16x32_bf16(a2, b1, acc[2][1], 0, 0, 0);
    }

    // pe one-hot K-steps (no LDS features, no barriers)
    int dc0 = sDcode[arow], dc1 = sDcode[arow + 16], dc2 = sDcode[arow + 32];
    #pragma unroll 1
    for (int kp = 0; kp < 3; ++kp) {
        int base = kp * 32 + kg * 8;
        bf16x8 a0, a1, a2;
        #pragma unroll
        for (int j = 0; j < 8; ++j) {
            a0[j] = (dc0 == base + j) ? (short)0x3F80 : (short)0;
            a1[j] = (dc1 == base + j) ? (short)0x3F80 : (short)0;
            a2[j] = (dc2 == base + j) ? (short)0x3F80 : (short)0;
        }
        const short* wp = wpBase + (size_t)(13 + kp) * K32S;
        bf16x8 b0 = *reinterpret_cast<const bf16x8*>(wp);
        bf16x8 b1 = *reinterpret_cast<const bf16x8*>(wp + 16 * 32);
        acc[0][0] = __builtin_amdgcn_mfma_f32_16x16x32_bf16(a0, b0, acc[0][0], 0, 0, 0);
        acc[1][0] = __builtin_amdgcn_mfma_f32_16x16x32_bf16(a1, b0, acc[1][0], 0, 0, 0);
        acc[2][0] = __builtin_amdgcn_mfma_f32_16x16x32_bf16(a2, b0, acc[2][0], 0, 0, 0);
        acc[0][1] = __builtin_amdgcn_mfma_f32_16x16x32_bf16(a0, b1, acc[0][1], 0, 0, 0);
        acc[1][1] = __builtin_amdgcn_mfma_f32_16x16x32_bf16(a1, b1, acc[1][1], 0, 0, 0);
        acc[2][1] = __builtin_amdgcn_mfma_f32_16x16x32_bf16(a2, b1, acc[2][1], 0, 0, 0);
    }

    // --------------------------- layernorm: cross-wave partials via LDS -----
    // C/D layout: col = (nt0+nb)*16 + arow, edge e = mt*16 + kg*4 + r
    #pragma unroll
    for (int mt = 0; mt < 3; ++mt)
        #pragma unroll
        for (int r = 0; r < 4; ++r) {
            float s = acc[mt][0][r] + acc[mt][1][r];
            float ss = acc[mt][0][r] * acc[mt][0][r]
                     + acc[mt][1][r] * acc[mt][1][r];
            s  += __shfl_xor(s, 1, 64);  ss += __shfl_xor(ss, 1, 64);
            s  += __shfl_xor(s, 2, 64);  ss += __shfl_xor(ss, 2, 64);
            s  += __shfl_xor(s, 4, 64);  ss += __shfl_xor(ss, 4, 64);
            s  += __shfl_xor(s, 8, 64);  ss += __shfl_xor(ss, 8, 64);
            if (arow == 0) {
                int e = mt * 16 + kg * 4 + r;
                sPartS[e][wid] = s;
                sPartSS[e][wid] = ss;
            }
        }
    __syncthreads();                                    // B16
    if (tid < KK) {
        float s = sPartS[tid][0] + sPartS[tid][1] + sPartS[tid][2] + sPartS[tid][3];
        float ss = sPartSS[tid][0] + sPartSS[tid][1] + sPartSS[tid][2] + sPartSS[tid][3];
        float mean = s * (1.0f / 128.0f);
        float var = ss * (1.0f / 128.0f) - mean * mean;
        sMean[tid] = mean;
        sInv[tid] = 1.0f / sqrtf(var + 1e-5f);
    }
    __syncthreads();                                    // B17

    // --------------------------------- normalize + store from registers -----
    const int col0 = nt0 * 16 + arow, col1 = col0 + 16;
    const float g0 = sGB[col0 * 2], be0 = sGB[col0 * 2 + 1];
    const float g1 = sGB[col1 * 2], be1 = sGB[col1 * 2 + 1];
    float* outR = outEdge + (size_t)row * KK * HH;
    #pragma unroll
    for (int mt = 0; mt < 3; ++mt)
        #pragma unroll
        for (int r = 0; r < 4; ++r) {
            int e = mt * 16 + kg * 4 + r;
            float mean = sMean[e], inv = sInv[e];
            outR[(size_t)e * HH + col0] = (acc[mt][0][r] - mean) * inv * g0 + be0;
            outR[(size_t)e * HH + col1] = (acc[mt][1][r] - mean) * inv * g1 + be1;
        }
}

// ---------------------------------------------------------------- launch ----
extern "C" void kernel_launch(void* const* d_in, const int* in_sizes, int n_in,
                              void* d_out, int out_size, void* d_ws, size_t ws_size,
                              hipStream_t stream) {
    const float* X     = (const float*)d_in[0];
    const float* mask  = (const float*)d_in[1];
    const int*   Ridx  = (const int*)d_in[2];
    const int*   chain = (const int*)d_in[3];
    const float* Wpos  = (const float*)d_in[4];
    const float* bpos  = (const float*)d_in[5];
    const float* Wedge = (const float*)d_in[6];
    const float* gamma = (const float*)d_in[7];
    const float* beta  = (const float*)d_in[8];

    float* outBase = (float*)d_out;
    float* outIdx  = outBase;                          // (B,L,K) f32
    float* outEdge = outBase + (size_t)BB * LL * KK;   // (B,L,K,H) f32

    short*  Wt  = (short*)d_ws;                                    // 128 KiB
    float4* caq = (float4*)((char*)d_ws + 16 * 8 * 16 * 32 * 2);   // 128 KiB

    hipLaunchKernelGGL(pf18_prep_w, dim3(256), dim3(256), 0, stream,
                       Wedge, Wpos, bpos, Wt);
    hipLaunchKernelGGL(pf18_prep_ca, dim3((BB * LL + 255) / 256), dim3(256), 0,
                       stream, X, mask, caq);
    hipLaunchKernelGGL(pf18_main, dim3(BB * LL), dim3(256), 0, stream,
                       X, Ridx, chain, gamma, beta, Wt, caq, outIdx, outEdge);
}

// Round 19
// 134.509 us; speedup vs baseline: 1.1102x; 1.1102x over previous
//
#include <hip/hip_runtime.h>
#include <hip/hip_bf16.h>

#define BB 4
#define LL 2048
#define KK 48
#define HH 128
#define CANDCAP 384
#define FSTR 40              // feat row stride (shorts)
#define DLT 1.06666666667f   // (4/3)*0.8
#define BINSCALE 2.0f        // linear d2 binning: 0.5 A^2 buckets

using bf16x8 = __attribute__((ext_vector_type(8))) short;
using f32x4  = __attribute__((ext_vector_type(4))) float;
using u64x2  = __attribute__((ext_vector_type(2))) unsigned long long;

// ---- prep 1: Wt fragment layout, 16 K-steps (13 rbf + 3 pe one-hot) --------
__global__ __launch_bounds__(256) void pf19_prep_w(
    const float* __restrict__ Wedge, const float* __restrict__ Wpos,
    const float* __restrict__ bpos, short* __restrict__ Wt) {
    int idx = blockIdx.x * 256 + threadIdx.x;          // 16*8*16*32 = 65536
    if (idx >= 16 * 8 * 16 * 32) return;
    int j  = idx & 7;
    int kg = (idx >> 3) & 3;
    int col = (idx >> 5) & 15;
    int nt = (idx >> 9) & 7;
    int kt = idx >> 12;
    int k = kt * 32 + kg * 8 + j;
    int n = nt * 16 + col;
    float v = 0.0f;
    if (kt < 13) {
        if (k < 400) v = Wedge[(size_t)(16 + k) * HH + n];
    } else {
        int d = k - 416;
        if (d < 66) {
            float s = 0.f;
            #pragma unroll
            for (int p = 0; p < 16; ++p)
                s += (Wpos[d * 16 + p] + bpos[p]) * Wedge[p * HH + n];
            v = s;
        }
    }
    __hip_bfloat16 h = __float2bfloat16(v);
    Wt[idx] = *reinterpret_cast<short*>(&h);
}

// ---- prep 2: packed CA + mask-bias table -----------------------------------
__global__ __launch_bounds__(256) void pf19_prep_ca(const float* __restrict__ X,
                                                    const float* __restrict__ mask,
                                                    float4* __restrict__ caq) {
    int i = blockIdx.x * 256 + threadIdx.x;            // B*L = 8192
    if (i >= BB * LL) return;
    const float* x = X + (size_t)i * 12;
    float bias = __fmul_rn(1.0f - mask[i], 1.0e6f);
    caq[i] = make_float4(x[3], x[4], x[5], bias);
}

// ---- main ------------------------------------------------------------------
__global__ __launch_bounds__(256, 6) void pf19_main(
    const float* __restrict__ X,
    const int* __restrict__ Ridx, const int* __restrict__ chain,
    const float* __restrict__ gamma, const float* __restrict__ beta,
    const short* __restrict__ Wt, const float4* __restrict__ caq,
    float* __restrict__ outIdx, float* __restrict__ outEdge) {

    const int row = blockIdx.x;             // b*L + l
    const int bq = row >> 11, lq = row & (LL - 1);
    const int tid = threadIdx.x;
    const int lane = tid & 63, wid = tid >> 6;
    const float* Xb = X + (size_t)bq * LL * 12;
    const float4* caqb = caq + (size_t)bq * LL;

    __shared__ __align__(16) union {
        int hist[1024];
        unsigned long long cand[CANDCAP];
        float geo[KK * 15 + 16];             // nb[48][15] + self @720
    } uA;
    __shared__ float sD[KK * 25];
    __shared__ __align__(16) short sFeat[2][KK * FSTR];
    __shared__ float sGB[2 * HH];
    __shared__ float sPartS[KK][4], sPartSS[KK][4];
    __shared__ float sMean[KK], sInv[KK];
    __shared__ int sSel[KK], sDcode[KK];
    __shared__ int sWsum[4];
    __shared__ int sBstar, sCc;

    if (tid < HH) { sGB[tid * 2] = gamma[tid]; sGB[tid * 2 + 1] = beta[tid]; }

    // ------------------------------------------------ top-k: distances ----
    const float4 sc = caqb[lq];
    float dval[8];
    #pragma unroll
    for (int i = 0; i < 8; ++i) {
        float4 q = caqb[i * 256 + tid];
        float dx = __fadd_rn(sc.x, -q.x);
        float dy = __fadd_rn(sc.y, -q.y);
        float dz = __fadd_rn(sc.z, -q.z);
        float d2 = __fadd_rn(__fadd_rn(__fmul_rn(dx, dx), __fmul_rn(dy, dy)),
                             __fmul_rn(dz, dz));
        dval[i] = __fadd_rn(d2, q.w);
    }

    *reinterpret_cast<int4*>(&uA.hist[tid * 4]) = make_int4(0, 0, 0, 0);
    if (tid == 0) sCc = 0;
    __syncthreads();                                    // B1
    #pragma unroll
    for (int i = 0; i < 8; ++i) {
        int bin = (int)(dval[i] * BINSCALE);
        bin = bin > 1023 ? 1023 : bin;
        atomicAdd(&uA.hist[bin], 1);
    }
    __syncthreads();                                    // B2

    int c0 = uA.hist[tid * 4 + 0];
    int c1 = uA.hist[tid * 4 + 1];
    int c2 = uA.hist[tid * 4 + 2];
    int c3 = uA.hist[tid * 4 + 3];
    int local = c0 + c1 + c2 + c3;
    int v = local;
    #pragma unroll
    for (int off = 1; off < 64; off <<= 1) {
        int o = __shfl_up(v, off, 64);
        if (lane >= off) v += o;
    }
    if (lane == 63) sWsum[wid] = v;
    __syncthreads();                                    // B3
    int woff = 0;
    #pragma unroll
    for (int w2 = 0; w2 < 4; ++w2) if (w2 < wid) woff += sWsum[w2];
    int incl = woff + v, excl = incl - local;
    if (excl < KK && incl >= KK) {
        int cum = excl, b = tid * 4;
        if (cum + c0 >= KK) sBstar = b;
        else { cum += c0;
            if (cum + c1 >= KK) sBstar = b + 1;
            else { cum += c1;
                if (cum + c2 >= KK) sBstar = b + 2;
                else sBstar = b + 3; } }
    }
    __syncthreads();                                    // B4 (hist dead)

    int bstar = sBstar;
    #pragma unroll
    for (int i = 0; i < 8; ++i) {
        int bin = (int)(dval[i] * BINSCALE);
        bin = bin > 1023 ? 1023 : bin;
        if (bin <= bstar) {
            int pos = atomicAdd(&sCc, 1);
            if (pos < CANDCAP)
                uA.cand[pos] =
                    ((unsigned long long)__float_as_uint(dval[i]) << 32)
                    | (unsigned)(i * 256 + tid);
        }
    }
    __syncthreads();                                    // B5

    // exact rank, vectorized candidate scan (ties -> lower index)
    int C = sCc < CANDCAP ? sCc : CANDCAP;
    for (int ci = tid; ci < C; ci += 256) {
        unsigned long long me = uA.cand[ci];
        int rank = 0, j2 = 0;
        int Cv = C & ~7;
        for (; j2 < Cv; j2 += 8) {
            u64x2 q0 = *reinterpret_cast<u64x2*>(&uA.cand[j2]);
            u64x2 q1 = *reinterpret_cast<u64x2*>(&uA.cand[j2 + 2]);
            u64x2 q2 = *reinterpret_cast<u64x2*>(&uA.cand[j2 + 4]);
            u64x2 q3 = *reinterpret_cast<u64x2*>(&uA.cand[j2 + 6]);
            rank += (q0[0] < me) + (q0[1] < me) + (q1[0] < me) + (q1[1] < me)
                  + (q2[0] < me) + (q2[1] < me) + (q3[0] < me) + (q3[1] < me);
        }
        for (; j2 < C; ++j2) rank += (uA.cand[j2] < me) ? 1 : 0;
        if (rank < KK) sSel[rank] = (int)(me & 0xFFFFFFFFu);
    }
    __syncthreads();                                    // B6 (cand dead)

    if (tid < KK) outIdx[(size_t)row * KK + tid] = (float)sSel[tid];

    // --------------------------------- neighbor atoms (with CB) + dcode ----
    const float KA = -0.58273431f, KB2 = 0.56802827f, KC = -0.54067466f;
    if (tid < KK) {
        int j = sSel[tid];
        const float* x = Xb + (size_t)j * 12;
        float u0 = x[3] - x[0], u1 = x[4] - x[1], u2 = x[5] - x[2];
        float w0 = x[6] - x[3], w1 = x[7] - x[4], w2 = x[8] - x[5];
        float r0 = u1 * w2 - u2 * w1;
        float r1 = u2 * w0 - u0 * w2;
        float r2 = u0 * w1 - u1 * w0;
        float* o = &uA.geo[tid * 15];
        #pragma unroll
        for (int t = 0; t < 12; ++t) o[t] = x[t];
        o[12] = KA * r0 + KB2 * u0 + KC * w0 + x[3];
        o[13] = KA * r1 + KB2 * u1 + KC * w1 + x[4];
        o[14] = KA * r2 + KB2 * u2 + KC * w2 + x[5];
        int offr = Ridx[row] - Ridx[(size_t)bq * LL + j];
        int same = (chain[row] == chain[(size_t)bq * LL + j]);
        int d = offr + 32;
        d = d < 0 ? 0 : (d > 64 ? 64 : d);
        sDcode[tid] = same ? d : 65;
    }
    if (tid == 64) {
        const float* x = Xb + (size_t)lq * 12;
        float u0 = x[3] - x[0], u1 = x[4] - x[1], u2 = x[5] - x[2];
        float w0 = x[6] - x[3], w1 = x[7] - x[4], w2 = x[8] - x[5];
        float r0 = u1 * w2 - u2 * w1;
        float r1 = u2 * w0 - u0 * w2;
        float r2 = u0 * w1 - u1 * w0;
        float* s = &uA.geo[720];
        #pragma unroll
        for (int t = 0; t < 12; ++t) s[t] = x[t];
        s[12] = KA * r0 + KB2 * u0 + KC * w0 + x[3];
        s[13] = KA * r1 + KB2 * u1 + KC * w1 + x[4];
        s[14] = KA * r2 + KB2 * u2 + KC * w2 + x[5];
    }
    __syncthreads();                                    // B7

    // ---------------------- pairwise distances (no integer division) --------
    #pragma unroll
    for (int it = 0; it < 6; ++it) {
        int idx = it * 256 + tid;
        int k = idx >> 5, pq = idx & 31;
        if (pq < 25) {
            int p = pq / 5, q = pq % 5;
            float dx = uA.geo[720 + p * 3 + 0] - uA.geo[k * 15 + q * 3 + 0];
            float dy = uA.geo[720 + p * 3 + 1] - uA.geo[k * 15 + q * 3 + 1];
            float dz = uA.geo[720 + p * 3 + 2] - uA.geo[k * 15 + q * 3 + 2];
            sD[k * 25 + pq] = sqrtf(dx * dx + dy * dy + dz * dz + 1e-6f);
        }
    }
    __syncthreads();                                    // B8

    // ------------------------------------- feature compute (one K-step) ----
    auto feat_compute = [&](int kt, int fb) {
        if (tid < 192) {
            int pair = tid >> 1, half = tid & 1;
            int k = pair >> 1, pq_lo = pair & 1;
            int pq = kt * 2 + pq_lo;
            bf16x8 ov;
            if (pq < 25) {
                float Dv = sD[k * 25 + pq];
                float t0 = (Dv - 2.0f) * 0.8f;
                float tm = __builtin_fmaf(-(float)(half << 3), DLT, t0);
                #pragma unroll
                for (int mi = 0; mi < 8; ++mi) {
                    float val = __expf(-tm * tm);
                    __hip_bfloat16 hb = __float2bfloat16(val);
                    ov[mi] = *reinterpret_cast<short*>(&hb);
                    tm -= DLT;
                }
            } else {
                #pragma unroll
                for (int mi = 0; mi < 8; ++mi) ov[mi] = 0;
            }
            *reinterpret_cast<bf16x8*>(
                &sFeat[fb][k * FSTR + pq_lo * 16 + (half << 3)]) = ov;
        }
    };

    feat_compute(0, 0);
    __syncthreads();                                    // B9

    // -------------------------------------------- MFMA GEMM, 13+3 K-steps ---
    f32x4 acc[3][2];
    #pragma unroll
    for (int mt = 0; mt < 3; ++mt)
        #pragma unroll
        for (int nb = 0; nb < 2; ++nb) acc[mt][nb] = (f32x4){0.f, 0.f, 0.f, 0.f};
    const int nt0 = wid * 2;
    const int arow = lane & 15, kg = lane >> 4;

    int cur = 0;
    #pragma unroll 1
    for (int kt = 0; kt < 13; ++kt) {
        const short* wp = Wt + (((size_t)(kt * 8 + nt0) * 16 + arow) * 32 + kg * 8);
        bf16x8 b0 = *reinterpret_cast<const bf16x8*>(wp);
        bf16x8 b1 = *reinterpret_cast<const bf16x8*>(wp + 16 * 32);
        if (kt + 1 < 13) feat_compute(kt + 1, cur ^ 1);
        bf16x8 a0 = *reinterpret_cast<const bf16x8*>(&sFeat[cur][(arow     ) * FSTR + kg * 8]);
        bf16x8 a1 = *reinterpret_cast<const bf16x8*>(&sFeat[cur][(arow + 16) * FSTR + kg * 8]);
        bf16x8 a2 = *reinterpret_cast<const bf16x8*>(&sFeat[cur][(arow + 32) * FSTR + kg * 8]);
        acc[0][0] = __builtin_amdgcn_mfma_f32_16x16x32_bf16(a0, b0, acc[0][0], 0, 0, 0);
        acc[1][0] = __builtin_amdgcn_mfma_f32_16x16x32_bf16(a1, b0, acc[1][0], 0, 0, 0);
        acc[2][0] = __builtin_amdgcn_mfma_f32_16x16x32_bf16(a2, b0, acc[2][0], 0, 0, 0);
        acc[0][1] = __builtin_amdgcn_mfma_f32_16x16x32_bf16(a0, b1, acc[0][1], 0, 0, 0);
        acc[1][1] = __builtin_amdgcn_mfma_f32_16x16x32_bf16(a1, b1, acc[1][1], 0, 0, 0);
        acc[2][1] = __builtin_amdgcn_mfma_f32_16x16x32_bf16(a2, b1, acc[2][1], 0, 0, 0);
        if (kt + 1 < 13) { __syncthreads(); cur ^= 1; }   // publish next buffer
    }

    // pe one-hot K-steps (no LDS features, no barriers)
    int dc0 = sDcode[arow], dc1 = sDcode[arow + 16], dc2 = sDcode[arow + 32];
    #pragma unroll 1
    for (int kp = 0; kp < 3; ++kp) {
        int base = kp * 32 + kg * 8;
        bf16x8 a0, a1, a2;
        #pragma unroll
        for (int j = 0; j < 8; ++j) {
            a0[j] = (dc0 == base + j) ? (short)0x3F80 : (short)0;
            a1[j] = (dc1 == base + j) ? (short)0x3F80 : (short)0;
            a2[j] = (dc2 == base + j) ? (short)0x3F80 : (short)0;
        }
        const short* wp = Wt + (((size_t)((13 + kp) * 8 + nt0) * 16 + arow) * 32 + kg * 8);
        bf16x8 b0 = *reinterpret_cast<const bf16x8*>(wp);
        bf16x8 b1 = *reinterpret_cast<const bf16x8*>(wp + 16 * 32);
        acc[0][0] = __builtin_amdgcn_mfma_f32_16x16x32_bf16(a0, b0, acc[0][0], 0, 0, 0);
        acc[1][0] = __builtin_amdgcn_mfma_f32_16x16x32_bf16(a1, b0, acc[1][0], 0, 0, 0);
        acc[2][0] = __builtin_amdgcn_mfma_f32_16x16x32_bf16(a2, b0, acc[2][0], 0, 0, 0);
        acc[0][1] = __builtin_amdgcn_mfma_f32_16x16x32_bf16(a0, b1, acc[0][1], 0, 0, 0);
        acc[1][1] = __builtin_amdgcn_mfma_f32_16x16x32_bf16(a1, b1, acc[1][1], 0, 0, 0);
        acc[2][1] = __builtin_amdgcn_mfma_f32_16x16x32_bf16(a2, b1, acc[2][1], 0, 0, 0);
    }

    // --------------------------- layernorm: cross-wave partials via LDS -----
    // C/D layout: col = (nt0+nb)*16 + arow, edge e = mt*16 + kg*4 + r
    #pragma unroll
    for (int mt = 0; mt < 3; ++mt)
        #pragma unroll
        for (int r = 0; r < 4; ++r) {
            float s = acc[mt][0][r] + acc[mt][1][r];
            float ss = acc[mt][0][r] * acc[mt][0][r]
                     + acc[mt][1][r] * acc[mt][1][r];
            s  += __shfl_xor(s, 1, 64);  ss += __shfl_xor(ss, 1, 64);
            s  += __shfl_xor(s, 2, 64);  ss += __shfl_xor(ss, 2, 64);
            s  += __shfl_xor(s, 4, 64);  ss += __shfl_xor(ss, 4, 64);
            s  += __shfl_xor(s, 8, 64);  ss += __shfl_xor(ss, 8, 64);
            if (arow == 0) {
                int e = mt * 16 + kg * 4 + r;
                sPartS[e][wid] = s;
                sPartSS[e][wid] = ss;
            }
        }
    __syncthreads();                                    // B10
    if (tid < KK) {
        float s = sPartS[tid][0] + sPartS[tid][1] + sPartS[tid][2] + sPartS[tid][3];
        float ss = sPartSS[tid][0] + sPartSS[tid][1] + sPartSS[tid][2] + sPartSS[tid][3];
        float mean = s * (1.0f / 128.0f);
        float var = ss * (1.0f / 128.0f) - mean * mean;
        sMean[tid] = mean;
        sInv[tid] = 1.0f / sqrtf(var + 1e-5f);
    }
    __syncthreads();                                    // B11

    // --------------------------------- normalize + store from registers -----
    const int col0 = nt0 * 16 + arow, col1 = col0 + 16;
    const float g0 = sGB[col0 * 2], be0 = sGB[col0 * 2 + 1];
    const float g1 = sGB[col1 * 2], be1 = sGB[col1 * 2 + 1];
    float* outR = outEdge + (size_t)row * KK * HH;
    #pragma unroll
    for (int mt = 0; mt < 3; ++mt)
        #pragma unroll
        for (int r = 0; r < 4; ++r) {
            int e = mt * 16 + kg * 4 + r;
            float mean = sMean[e], inv = sInv[e];
            outR[(size_t)e * HH + col0] = (acc[mt][0][r] - mean) * inv * g0 + be0;
            outR[(size_t)e * HH + col1] = (acc[mt][1][r] - mean) * inv * g1 + be1;
        }
}

// ---------------------------------------------------------------- launch ----
extern "C" void kernel_launch(void* const* d_in, const int* in_sizes, int n_in,
                              void* d_out, int out_size, void* d_ws, size_t ws_size,
                              hipStream_t stream) {
    const float* X     = (const float*)d_in[0];
    const float* mask  = (const float*)d_in[1];
    const int*   Ridx  = (const int*)d_in[2];
    const int*   chain = (const int*)d_in[3];
    const float* Wpos  = (const float*)d_in[4];
    const float* bpos  = (const float*)d_in[5];
    const float* Wedge = (const float*)d_in[6];
    const float* gamma = (const float*)d_in[7];
    const float* beta  = (const float*)d_in[8];

    float* outBase = (float*)d_out;
    float* outIdx  = outBase;                          // (B,L,K) f32
    float* outEdge = outBase + (size_t)BB * LL * KK;   // (B,L,K,H) f32

    short*  Wt  = (short*)d_ws;                                    // 128 KiB
    float4* caq = (float4*)((char*)d_ws + 16 * 8 * 16 * 32 * 2);   // 128 KiB

    hipLaunchKernelGGL(pf19_prep_w, dim3(256), dim3(256), 0, stream,
                       Wedge, Wpos, bpos, Wt);
    hipLaunchKernelGGL(pf19_prep_ca, dim3((BB * LL + 255) / 256), dim3(256), 0,
                       stream, X, mask, caq);
    hipLaunchKernelGGL(pf19_main, dim3(BB * LL), dim3(256), 0, stream,
                       X, Ridx, chain, gamma, beta, Wt, caq, outIdx, outEdge);
}

// Round 21
// 131.643 us; speedup vs baseline: 1.1344x; 1.0218x over previous
//
#include <hip/hip_runtime.h>
#include <hip/hip_bf16.h>

#define BB 4
#define LL 2048
#define KK 48
#define HH 128
#define CANDCAP 384
#define FSTR 40              // feat row stride (shorts)
#define DLT 1.06666666667f   // (4/3)*0.8
#define BINSCALE 2.0f        // linear d2 binning: 0.5 A^2 buckets
#define L2E 1.44269504089f
#define EXP_2DT 3.0777494f   // 2*DLT*L2E
#define KC1 0.32053064f      // exp(-DLT^2)
#define KC2 0.10273989f      // exp(-2*DLT^2)
#define TM_CLAMP 10.24f      // overflow guard: all true values < 5e-4 past this

using bf16x8 = __attribute__((ext_vector_type(8))) short;
using f32x4  = __attribute__((ext_vector_type(4))) float;
using u64x2  = __attribute__((ext_vector_type(2))) unsigned long long;

// ---- prep 1: Wt fragment layout, 16 K-steps (13 rbf + 3 pe one-hot) --------
__global__ __launch_bounds__(256) void pf21_prep_w(
    const float* __restrict__ Wedge, const float* __restrict__ Wpos,
    const float* __restrict__ bpos, short* __restrict__ Wt) {
    int idx = blockIdx.x * 256 + threadIdx.x;          // 16*8*16*32 = 65536
    if (idx >= 16 * 8 * 16 * 32) return;
    int j  = idx & 7;
    int kg = (idx >> 3) & 3;
    int col = (idx >> 5) & 15;
    int nt = (idx >> 9) & 7;
    int kt = idx >> 12;
    int k = kt * 32 + kg * 8 + j;
    int n = nt * 16 + col;
    float v = 0.0f;
    if (kt < 13) {
        if (k < 400) v = Wedge[(size_t)(16 + k) * HH + n];
    } else {
        int d = k - 416;
        if (d < 66) {
            float s = 0.f;
            #pragma unroll
            for (int p = 0; p < 16; ++p)
                s += (Wpos[d * 16 + p] + bpos[p]) * Wedge[p * HH + n];
            v = s;
        }
    }
    __hip_bfloat16 h = __float2bfloat16(v);
    Wt[idx] = *reinterpret_cast<short*>(&h);
}

// ---- prep 2: packed CA + mask-bias table -----------------------------------
__global__ __launch_bounds__(256) void pf21_prep_ca(const float* __restrict__ X,
                                                    const float* __restrict__ mask,
                                                    float4* __restrict__ caq) {
    int i = blockIdx.x * 256 + threadIdx.x;            // B*L = 8192
    if (i >= BB * LL) return;
    const float* x = X + (size_t)i * 12;
    float bias = __fmul_rn(1.0f - mask[i], 1.0e6f);
    caq[i] = make_float4(x[3], x[4], x[5], bias);
}

// ---- main ------------------------------------------------------------------
__global__ __launch_bounds__(256, 6) void pf21_main(
    const float* __restrict__ X,
    const int* __restrict__ Ridx, const int* __restrict__ chain,
    const float* __restrict__ gamma, const float* __restrict__ beta,
    const short* __restrict__ Wt, const float4* __restrict__ caq,
    float* __restrict__ outIdx, float* __restrict__ outEdge) {

    const int row = blockIdx.x;             // b*L + l
    const int bq = row >> 11, lq = row & (LL - 1);
    const int tid = threadIdx.x;
    const int lane = tid & 63, wid = tid >> 6;
    const float* Xb = X + (size_t)bq * LL * 12;
    const float4* caqb = caq + (size_t)bq * LL;

    __shared__ __align__(16) union {
        int hist[1024];
        unsigned long long cand[CANDCAP];
        float geo[KK * 15 + 16];             // nb[48][15] + self @720
    } uA;
    __shared__ float sD[KK * 25];
    __shared__ __align__(16) short sFeat[2][KK * FSTR];
    __shared__ float sGB[2 * HH];
    __shared__ float sPartS[KK][4], sPartSS[KK][4];
    __shared__ float sMean[KK], sInv[KK];
    __shared__ int sSel[KK], sDcode[KK];
    __shared__ int sWsum[4];
    __shared__ int sBstar, sCc;

    if (tid < HH) { sGB[tid * 2] = gamma[tid]; sGB[tid * 2 + 1] = beta[tid]; }

    // ------------------------------------------------ top-k: distances ----
    const float4 sc = caqb[lq];
    float dval[8];
    #pragma unroll
    for (int i = 0; i < 8; ++i) {
        float4 q = caqb[i * 256 + tid];
        float dx = __fadd_rn(sc.x, -q.x);
        float dy = __fadd_rn(sc.y, -q.y);
        float dz = __fadd_rn(sc.z, -q.z);
        float d2 = __fadd_rn(__fadd_rn(__fmul_rn(dx, dx), __fmul_rn(dy, dy)),
                             __fmul_rn(dz, dz));
        dval[i] = __fadd_rn(d2, q.w);
    }

    *reinterpret_cast<int4*>(&uA.hist[tid * 4]) = make_int4(0, 0, 0, 0);
    if (tid == 0) sCc = 0;
    __syncthreads();                                    // B1
    #pragma unroll
    for (int i = 0; i < 8; ++i) {
        int bin = (int)(dval[i] * BINSCALE);
        bin = bin > 1023 ? 1023 : bin;
        atomicAdd(&uA.hist[bin], 1);
    }
    __syncthreads();                                    // B2

    int c0 = uA.hist[tid * 4 + 0];
    int c1 = uA.hist[tid * 4 + 1];
    int c2 = uA.hist[tid * 4 + 2];
    int c3 = uA.hist[tid * 4 + 3];
    int local = c0 + c1 + c2 + c3;
    int v = local;
    #pragma unroll
    for (int off = 1; off < 64; off <<= 1) {
        int o = __shfl_up(v, off, 64);
        if (lane >= off) v += o;
    }
    if (lane == 63) sWsum[wid] = v;
    __syncthreads();                                    // B3
    int woff = 0;
    #pragma unroll
    for (int w2 = 0; w2 < 4; ++w2) if (w2 < wid) woff += sWsum[w2];
    int incl = woff + v, excl = incl - local;
    if (excl < KK && incl >= KK) {
        int cum = excl, b = tid * 4;
        if (cum + c0 >= KK) sBstar = b;
        else { cum += c0;
            if (cum + c1 >= KK) sBstar = b + 1;
            else { cum += c1;
                if (cum + c2 >= KK) sBstar = b + 2;
                else sBstar = b + 3; } }
    }
    __syncthreads();                                    // B4 (hist dead)

    int bstar = sBstar;
    #pragma unroll
    for (int i = 0; i < 8; ++i) {
        int bin = (int)(dval[i] * BINSCALE);
        bin = bin > 1023 ? 1023 : bin;
        if (bin <= bstar) {
            int pos = atomicAdd(&sCc, 1);
            if (pos < CANDCAP)
                uA.cand[pos] =
                    ((unsigned long long)__float_as_uint(dval[i]) << 32)
                    | (unsigned)(i * 256 + tid);
        }
    }
    __syncthreads();                                    // B5

    // exact rank, vectorized candidate scan (ties -> lower index)
    int C = sCc < CANDCAP ? sCc : CANDCAP;
    for (int ci = tid; ci < C; ci += 256) {
        unsigned long long me = uA.cand[ci];
        int rank = 0, j2 = 0;
        int Cv = C & ~7;
        for (; j2 < Cv; j2 += 8) {
            u64x2 q0 = *reinterpret_cast<u64x2*>(&uA.cand[j2]);
            u64x2 q1 = *reinterpret_cast<u64x2*>(&uA.cand[j2 + 2]);
            u64x2 q2 = *reinterpret_cast<u64x2*>(&uA.cand[j2 + 4]);
            u64x2 q3 = *reinterpret_cast<u64x2*>(&uA.cand[j2 + 6]);
            rank += (q0[0] < me) + (q0[1] < me) + (q1[0] < me) + (q1[1] < me)
                  + (q2[0] < me) + (q2[1] < me) + (q3[0] < me) + (q3[1] < me);
        }
        for (; j2 < C; ++j2) rank += (uA.cand[j2] < me) ? 1 : 0;
        if (rank < KK) sSel[rank] = (int)(me & 0xFFFFFFFFu);
    }
    __syncthreads();                                    // B6 (cand dead)

    if (tid < KK) outIdx[(size_t)row * KK + tid] = (float)sSel[tid];

    // --------------------------------- neighbor atoms (with CB) + dcode ----
    const float KA = -0.58273431f, KB2 = 0.56802827f, KC = -0.54067466f;
    if (tid < KK) {
        int j = sSel[tid];
        const float* x = Xb + (size_t)j * 12;
        float u0 = x[3] - x[0], u1 = x[4] - x[1], u2 = x[5] - x[2];
        float w0 = x[6] - x[3], w1 = x[7] - x[4], w2 = x[8] - x[5];
        float r0 = u1 * w2 - u2 * w1;
        float r1 = u2 * w0 - u0 * w2;
        float r2 = u0 * w1 - u1 * w0;
        float* o = &uA.geo[tid * 15];
        #pragma unroll
        for (int t = 0; t < 12; ++t) o[t] = x[t];
        o[12] = KA * r0 + KB2 * u0 + KC * w0 + x[3];
        o[13] = KA * r1 + KB2 * u1 + KC * w1 + x[4];
        o[14] = KA * r2 + KB2 * u2 + KC * w2 + x[5];
        int offr = Ridx[row] - Ridx[(size_t)bq * LL + j];
        int same = (chain[row] == chain[(size_t)bq * LL + j]);
        int d = offr + 32;
        d = d < 0 ? 0 : (d > 64 ? 64 : d);
        sDcode[tid] = same ? d : 65;
    }
    if (tid == 64) {
        const float* x = Xb + (size_t)lq * 12;
        float u0 = x[3] - x[0], u1 = x[4] - x[1], u2 = x[5] - x[2];
        float w0 = x[6] - x[3], w1 = x[7] - x[4], w2 = x[8] - x[5];
        float r0 = u1 * w2 - u2 * w1;
        float r1 = u2 * w0 - u0 * w2;
        float r2 = u0 * w1 - u1 * w0;
        float* s = &uA.geo[720];
        #pragma unroll
        for (int t = 0; t < 12; ++t) s[t] = x[t];
        s[12] = KA * r0 + KB2 * u0 + KC * w0 + x[3];
        s[13] = KA * r1 + KB2 * u1 + KC * w1 + x[4];
        s[14] = KA * r2 + KB2 * u2 + KC * w2 + x[5];
    }
    __syncthreads();                                    // B7

    // ---------------------- pairwise distances (no integer division) --------
    #pragma unroll
    for (int it = 0; it < 6; ++it) {
        int idx = it * 256 + tid;
        int k = idx >> 5, pq = idx & 31;
        if (pq < 25) {
            int p = pq / 5, q = pq % 5;
            float dx = uA.geo[720 + p * 3 + 0] - uA.geo[k * 15 + q * 3 + 0];
            float dy = uA.geo[720 + p * 3 + 1] - uA.geo[k * 15 + q * 3 + 1];
            float dz = uA.geo[720 + p * 3 + 2] - uA.geo[k * 15 + q * 3 + 2];
            sD[k * 25 + pq] = sqrtf(dx * dx + dy * dy + dz * dz + 1e-6f);
        }
    }
    __syncthreads();                                    // B8

    // --------- feature compute: Gaussian ladder via multiplicative chain ----
    // v_{m+1} = v_m * s,  s_{m+1} = s * KC2; s_0 = e^{2*DLT*tm}*KC1.
    // tm clamped at TM_CLAMP: prevents s overflow (0*inf=NaN); for clamped
    // cases all true values < 5e-4, clamp error << tolerance.
    auto feat_compute = [&](int kt, int fb) {
        if (tid < 192) {
            int pair = tid >> 1, half = tid & 1;
            int k = pair >> 1, pq_lo = pair & 1;
            int pq = kt * 2 + pq_lo;
            bf16x8 ov;
            if (pq < 25) {
                float Dv = sD[k * 25 + pq];
                float t0 = (Dv - 2.0f) * 0.8f;
                float tm = __builtin_fmaf(-(float)(half << 3), DLT, t0);
                tm = fminf(tm, TM_CLAMP);
                float vv = exp2f(-(tm * tm) * L2E);       // exp(-tm^2)
                float s  = exp2f(EXP_2DT * tm) * KC1;     // e^{2*DLT*tm - DLT^2}
                __hip_bfloat16 hb = __float2bfloat16(vv);
                ov[0] = *reinterpret_cast<short*>(&hb);
                #pragma unroll
                for (int mi = 1; mi < 8; ++mi) {
                    vv *= s;
                    s  *= KC2;
                    hb = __float2bfloat16(vv);
                    ov[mi] = *reinterpret_cast<short*>(&hb);
                }
            } else {
                #pragma unroll
                for (int mi = 0; mi < 8; ++mi) ov[mi] = 0;
            }
            *reinterpret_cast<bf16x8*>(
                &sFeat[fb][k * FSTR + pq_lo * 16 + (half << 3)]) = ov;
        }
    };

    feat_compute(0, 0);
    __syncthreads();                                    // B9

    // -------------------------------------------- MFMA GEMM, 13+3 K-steps ---
    f32x4 acc[3][2];
    #pragma unroll
    for (int mt = 0; mt < 3; ++mt)
        #pragma unroll
        for (int nb = 0; nb < 2; ++nb) acc[mt][nb] = (f32x4){0.f, 0.f, 0.f, 0.f};
    const int nt0 = wid * 2;
    const int arow = lane & 15, kg = lane >> 4;

    int cur = 0;
    #pragma unroll 1
    for (int kt = 0; kt < 13; ++kt) {
        const short* wp = Wt + (((size_t)(kt * 8 + nt0) * 16 + arow) * 32 + kg * 8);
        bf16x8 b0 = *reinterpret_cast<const bf16x8*>(wp);
        bf16x8 b1 = *reinterpret_cast<const bf16x8*>(wp + 16 * 32);
        if (kt + 1 < 13) feat_compute(kt + 1, cur ^ 1);
        bf16x8 a0 = *reinterpret_cast<const bf16x8*>(&sFeat[cur][(arow     ) * FSTR + kg * 8]);
        bf16x8 a1 = *reinterpret_cast<const bf16x8*>(&sFeat[cur][(arow + 16) * FSTR + kg * 8]);
        bf16x8 a2 = *reinterpret_cast<const bf16x8*>(&sFeat[cur][(arow + 32) * FSTR + kg * 8]);
        acc[0][0] = __builtin_amdgcn_mfma_f32_16x16x32_bf16(a0, b0, acc[0][0], 0, 0, 0);
        acc[1][0] = __builtin_amdgcn_mfma_f32_16x16x32_bf16(a1, b0, acc[1][0], 0, 0, 0);
        acc[2][0] = __builtin_amdgcn_mfma_f32_16x16x32_bf16(a2, b0, acc[2][0], 0, 0, 0);
        acc[0][1] = __builtin_amdgcn_mfma_f32_16x16x32_bf16(a0, b1, acc[0][1], 0, 0, 0);
        acc[1][1] = __builtin_amdgcn_mfma_f32_16x16x32_bf16(a1, b1, acc[1][1], 0, 0, 0);
        acc[2][1] = __builtin_amdgcn_mfma_f32_16x16x32_bf16(a2, b1, acc[2][1], 0, 0, 0);
        if (kt + 1 < 13) { __syncthreads(); cur ^= 1; }   // publish next buffer
    }

    // pe one-hot K-steps (no LDS features, no barriers)
    int dc0 = sDcode[arow], dc1 = sDcode[arow + 16], dc2 = sDcode[arow + 32];
    #pragma unroll 1
    for (int kp = 0; kp < 3; ++kp) {
        int base = kp * 32 + kg * 8;
        bf16x8 a0, a1, a2;
        #pragma unroll
        for (int j = 0; j < 8; ++j) {
            a0[j] = (dc0 == base + j) ? (short)0x3F80 : (short)0;
            a1[j] = (dc1 == base + j) ? (short)0x3F80 : (short)0;
            a2[j] = (dc2 == base + j) ? (short)0x3F80 : (short)0;
        }
        const short* wp = Wt + (((size_t)((13 + kp) * 8 + nt0) * 16 + arow) * 32 + kg * 8);
        bf16x8 b0 = *reinterpret_cast<const bf16x8*>(wp);
        bf16x8 b1 = *reinterpret_cast<const bf16x8*>(wp + 16 * 32);
        acc[0][0] = __builtin_amdgcn_mfma_f32_16x16x32_bf16(a0, b0, acc[0][0], 0, 0, 0);
        acc[1][0] = __builtin_amdgcn_mfma_f32_16x16x32_bf16(a1, b0, acc[1][0], 0, 0, 0);
        acc[2][0] = __builtin_amdgcn_mfma_f32_16x16x32_bf16(a2, b0, acc[2][0], 0, 0, 0);
        acc[0][1] = __builtin_amdgcn_mfma_f32_16x16x32_bf16(a0, b1, acc[0][1], 0, 0, 0);
        acc[1][1] = __builtin_amdgcn_mfma_f32_16x16x32_bf16(a1, b1, acc[1][1], 0, 0, 0);
        acc[2][1] = __builtin_amdgcn_mfma_f32_16x16x32_bf16(a2, b1, acc[2][1], 0, 0, 0);
    }

    // --------------------------- layernorm: cross-wave partials via LDS -----
    // C/D layout: col = (nt0+nb)*16 + arow, edge e = mt*16 + kg*4 + r
    #pragma unroll
    for (int mt = 0; mt < 3; ++mt)
        #pragma unroll
        for (int r = 0; r < 4; ++r) {
            float s = acc[mt][0][r] + acc[mt][1][r];
            float ss = acc[mt][0][r] * acc[mt][0][r]
                     + acc[mt][1][r] * acc[mt][1][r];
            s  += __shfl_xor(s, 1, 64);  ss += __shfl_xor(ss, 1, 64);
            s  += __shfl_xor(s, 2, 64);  ss += __shfl_xor(ss, 2, 64);
            s  += __shfl_xor(s, 4, 64);  ss += __shfl_xor(ss, 4, 64);
            s  += __shfl_xor(s, 8, 64);  ss += __shfl_xor(ss, 8, 64);
            if (arow == 0) {
                int e = mt * 16 + kg * 4 + r;
                sPartS[e][wid] = s;
                sPartSS[e][wid] = ss;
            }
        }
    __syncthreads();                                    // B10
    if (tid < KK) {
        float s = sPartS[tid][0] + sPartS[tid][1] + sPartS[tid][2] + sPartS[tid][3];
        float ss = sPartSS[tid][0] + sPartSS[tid][1] + sPartSS[tid][2] + sPartSS[tid][3];
        float mean = s * (1.0f / 128.0f);
        float var = ss * (1.0f / 128.0f) - mean * mean;
        sMean[tid] = mean;
        sInv[tid] = 1.0f / sqrtf(var + 1e-5f);
    }
    __syncthreads();                                    // B11

    // --------------------------------- normalize + store from registers -----
    const int col0 = nt0 * 16 + arow, col1 = col0 + 16;
    const float g0 = sGB[col0 * 2], be0 = sGB[col0 * 2 + 1];
    const float g1 = sGB[col1 * 2], be1 = sGB[col1 * 2 + 1];
    float* outR = outEdge + (size_t)row * KK * HH;
    #pragma unroll
    for (int mt = 0; mt < 3; ++mt)
        #pragma unroll
        for (int r = 0; r < 4; ++r) {
            int e = mt * 16 + kg * 4 + r;
            float mean = sMean[e], inv = sInv[e];
            outR[(size_t)e * HH + col0] = (acc[mt][0][r] - mean) * inv * g0 + be0;
            outR[(size_t)e * HH + col1] = (acc[mt][1][r] - mean) * inv * g1 + be1;
        }
}

// ---------------------------------------------------------------- launch ----
extern "C" void kernel_launch(void* const* d_in, const int* in_sizes, int n_in,
                              void* d_out, int out_size, void* d_ws, size_t ws_size,
                              hipStream_t stream) {
    const float* X     = (const float*)d_in[0];
    const float* mask  = (const float*)d_in[1];
    const int*   Ridx  = (const int*)d_in[2];
    const int*   chain = (const int*)d_in[3];
    const float* Wpos  = (const float*)d_in[4];
    const float* bpos  = (const float*)d_in[5];
    const float* Wedge = (const float*)d_in[6];
    const float* gamma = (const float*)d_in[7];
    const float* beta  = (const float*)d_in[8];

    float* outBase = (float*)d_out;
    float* outIdx  = outBase;                          // (B,L,K) f32
    float* outEdge = outBase + (size_t)BB * LL * KK;   // (B,L,K,H) f32

    short*  Wt  = (short*)d_ws;                                    // 128 KiB
    float4* caq = (float4*)((char*)d_ws + 16 * 8 * 16 * 32 * 2);   // 128 KiB

    hipLaunchKernelGGL(pf21_prep_w, dim3(256), dim3(256), 0, stream,
                       Wedge, Wpos, bpos, Wt);
    hipLaunchKernelGGL(pf21_prep_ca, dim3((BB * LL + 255) / 256), dim3(256), 0,
                       stream, X, mask, caq);
    hipLaunchKernelGGL(pf21_main, dim3(BB * LL), dim3(256), 0, stream,
                       X, Ridx, chain, gamma, beta, Wt, caq, outIdx, outEdge);
}

// Round 22
// 130.800 us; speedup vs baseline: 1.1417x; 1.0064x over previous
//
#include <hip/hip_runtime.h>
#include <hip/hip_bf16.h>

#define BB 4
#define LL 2048
#define KK 48
#define HH 128
#define CANDCAP 384
#define FSTR 40              // feat row stride (shorts)
#define DLT 1.06666666667f   // (4/3)*0.8
#define BINSCALE 2.0f        // linear d2 binning: 0.5 A^2 buckets
#define L2E 1.44269504089f
#define EXP_2DT 3.0777494f   // 2*DLT*L2E
#define KC1 0.32053064f      // exp(-DLT^2)
#define KC2 0.10273989f      // exp(-2*DLT^2)
#define TM_CLAMP 10.24f      // overflow guard for the multiplicative chain

using bf16x8 = __attribute__((ext_vector_type(8))) short;
using f32x4  = __attribute__((ext_vector_type(4))) float;
using u64x2  = __attribute__((ext_vector_type(2))) unsigned long long;

// ---- prep 1: Wt fragment layout, 16 K-steps (13 rbf + 3 pe one-hot) --------
__global__ __launch_bounds__(256) void pf22_prep_w(
    const float* __restrict__ Wedge, const float* __restrict__ Wpos,
    const float* __restrict__ bpos, short* __restrict__ Wt) {
    int idx = blockIdx.x * 256 + threadIdx.x;          // 16*8*16*32 = 65536
    if (idx >= 16 * 8 * 16 * 32) return;
    int j  = idx & 7;
    int kg = (idx >> 3) & 3;
    int col = (idx >> 5) & 15;
    int nt = (idx >> 9) & 7;
    int kt = idx >> 12;
    int k = kt * 32 + kg * 8 + j;
    int n = nt * 16 + col;
    float v = 0.0f;
    if (kt < 13) {
        if (k < 400) v = Wedge[(size_t)(16 + k) * HH + n];
    } else {
        int d = k - 416;
        if (d < 66) {
            float s = 0.f;
            #pragma unroll
            for (int p = 0; p < 16; ++p)
                s += (Wpos[d * 16 + p] + bpos[p]) * Wedge[p * HH + n];
            v = s;
        }
    }
    __hip_bfloat16 h = __float2bfloat16(v);
    Wt[idx] = *reinterpret_cast<short*>(&h);
}

// ---- prep 2: packed CA + mask-bias table -----------------------------------
__global__ __launch_bounds__(256) void pf22_prep_ca(const float* __restrict__ X,
                                                    const float* __restrict__ mask,
                                                    float4* __restrict__ caq) {
    int i = blockIdx.x * 256 + threadIdx.x;            // B*L = 8192
    if (i >= BB * LL) return;
    const float* x = X + (size_t)i * 12;
    float bias = __fmul_rn(1.0f - mask[i], 1.0e6f);
    caq[i] = make_float4(x[3], x[4], x[5], bias);
}

// ---- main ------------------------------------------------------------------
__global__ __launch_bounds__(256, 6) void pf22_main(
    const float* __restrict__ X,
    const int* __restrict__ Ridx, const int* __restrict__ chain,
    const float* __restrict__ gamma, const float* __restrict__ beta,
    const short* __restrict__ Wt, const float4* __restrict__ caq,
    float* __restrict__ outIdx, float* __restrict__ outEdge) {

    const int row = blockIdx.x;             // b*L + l
    const int bq = row >> 11, lq = row & (LL - 1);
    const int tid = threadIdx.x;
    const int lane = tid & 63, wid = tid >> 6;
    const float* Xb = X + (size_t)bq * LL * 12;
    const float4* caqb = caq + (size_t)bq * LL;

    __shared__ __align__(16) union {
        int hist[1024];
        unsigned long long cand[CANDCAP];
        float geo[KK * 15 + 16];             // nb[48][15] + self @720
    } uA;
    __shared__ float sD[KK * 25];
    __shared__ __align__(16) short sFeat[2][KK * FSTR];
    __shared__ float sGB[2 * HH];
    __shared__ float sPartS[KK][4], sPartSS[KK][4];
    __shared__ float sMean[KK], sInv[KK];
    __shared__ int sSel[KK], sDcode[KK];
    __shared__ int sWsum[4];
    __shared__ int sBstar, sCc;

    if (tid < HH) { sGB[tid * 2] = gamma[tid]; sGB[tid * 2 + 1] = beta[tid]; }

    // ------------------------------------------------ top-k: distances ----
    const float4 sc = caqb[lq];
    float dval[8];
    #pragma unroll
    for (int i = 0; i < 8; ++i) {
        float4 q = caqb[i * 256 + tid];
        float dx = __fadd_rn(sc.x, -q.x);
        float dy = __fadd_rn(sc.y, -q.y);
        float dz = __fadd_rn(sc.z, -q.z);
        float d2 = __fadd_rn(__fadd_rn(__fmul_rn(dx, dx), __fmul_rn(dy, dy)),
                             __fmul_rn(dz, dz));
        dval[i] = __fadd_rn(d2, q.w);
    }

    *reinterpret_cast<int4*>(&uA.hist[tid * 4]) = make_int4(0, 0, 0, 0);
    if (tid == 0) sCc = 0;
    __syncthreads();                                    // B1
    #pragma unroll
    for (int i = 0; i < 8; ++i) {
        int bin = (int)(dval[i] * BINSCALE);
        bin = bin > 1023 ? 1023 : bin;
        atomicAdd(&uA.hist[bin], 1);
    }
    __syncthreads();                                    // B2

    int c0 = uA.hist[tid * 4 + 0];
    int c1 = uA.hist[tid * 4 + 1];
    int c2 = uA.hist[tid * 4 + 2];
    int c3 = uA.hist[tid * 4 + 3];
    int local = c0 + c1 + c2 + c3;
    int v = local;
    #pragma unroll
    for (int off = 1; off < 64; off <<= 1) {
        int o = __shfl_up(v, off, 64);
        if (lane >= off) v += o;
    }
    if (lane == 63) sWsum[wid] = v;
    __syncthreads();                                    // B3
    int woff = 0;
    #pragma unroll
    for (int w2 = 0; w2 < 4; ++w2) if (w2 < wid) woff += sWsum[w2];
    int incl = woff + v, excl = incl - local;
    if (excl < KK && incl >= KK) {
        int cum = excl, b = tid * 4;
        if (cum + c0 >= KK) sBstar = b;
        else { cum += c0;
            if (cum + c1 >= KK) sBstar = b + 1;
            else { cum += c1;
                if (cum + c2 >= KK) sBstar = b + 2;
                else sBstar = b + 3; } }
    }
    __syncthreads();                                    // B4 (hist dead)

    int bstar = sBstar;
    #pragma unroll
    for (int i = 0; i < 8; ++i) {
        int bin = (int)(dval[i] * BINSCALE);
        bin = bin > 1023 ? 1023 : bin;
        if (bin <= bstar) {
            int pos = atomicAdd(&sCc, 1);
            if (pos < CANDCAP)
                uA.cand[pos] =
                    ((unsigned long long)__float_as_uint(dval[i]) << 32)
                    | (unsigned)(i * 256 + tid);
        }
    }
    __syncthreads();                                    // B5

    // exact rank, vectorized candidate scan (ties -> lower index)
    int C = sCc < CANDCAP ? sCc : CANDCAP;
    for (int ci = tid; ci < C; ci += 256) {
        unsigned long long me = uA.cand[ci];
        int rank = 0, j2 = 0;
        int Cv = C & ~7;
        for (; j2 < Cv; j2 += 8) {
            u64x2 q0 = *reinterpret_cast<u64x2*>(&uA.cand[j2]);
            u64x2 q1 = *reinterpret_cast<u64x2*>(&uA.cand[j2 + 2]);
            u64x2 q2 = *reinterpret_cast<u64x2*>(&uA.cand[j2 + 4]);
            u64x2 q3 = *reinterpret_cast<u64x2*>(&uA.cand[j2 + 6]);
            rank += (q0[0] < me) + (q0[1] < me) + (q1[0] < me) + (q1[1] < me)
                  + (q2[0] < me) + (q2[1] < me) + (q3[0] < me) + (q3[1] < me);
        }
        for (; j2 < C; ++j2) rank += (uA.cand[j2] < me) ? 1 : 0;
        if (rank < KK) sSel[rank] = (int)(me & 0xFFFFFFFFu);
    }
    __syncthreads();                                    // B6 (cand dead)

    if (tid < KK) outIdx[(size_t)row * KK + tid] = (float)sSel[tid];

    // --------------------------------- neighbor atoms (with CB) + dcode ----
    const float KA = -0.58273431f, KB2 = 0.56802827f, KC = -0.54067466f;
    if (tid < KK) {
        int j = sSel[tid];
        const float* x = Xb + (size_t)j * 12;
        float u0 = x[3] - x[0], u1 = x[4] - x[1], u2 = x[5] - x[2];
        float w0 = x[6] - x[3], w1 = x[7] - x[4], w2 = x[8] - x[5];
        float r0 = u1 * w2 - u2 * w1;
        float r1 = u2 * w0 - u0 * w2;
        float r2 = u0 * w1 - u1 * w0;
        float* o = &uA.geo[tid * 15];
        #pragma unroll
        for (int t = 0; t < 12; ++t) o[t] = x[t];
        o[12] = KA * r0 + KB2 * u0 + KC * w0 + x[3];
        o[13] = KA * r1 + KB2 * u1 + KC * w1 + x[4];
        o[14] = KA * r2 + KB2 * u2 + KC * w2 + x[5];
        int offr = Ridx[row] - Ridx[(size_t)bq * LL + j];
        int same = (chain[row] == chain[(size_t)bq * LL + j]);
        int d = offr + 32;
        d = d < 0 ? 0 : (d > 64 ? 64 : d);
        sDcode[tid] = same ? d : 65;
    }
    if (tid == 64) {
        const float* x = Xb + (size_t)lq * 12;
        float u0 = x[3] - x[0], u1 = x[4] - x[1], u2 = x[5] - x[2];
        float w0 = x[6] - x[3], w1 = x[7] - x[4], w2 = x[8] - x[5];
        float r0 = u1 * w2 - u2 * w1;
        float r1 = u2 * w0 - u0 * w2;
        float r2 = u0 * w1 - u1 * w0;
        float* s = &uA.geo[720];
        #pragma unroll
        for (int t = 0; t < 12; ++t) s[t] = x[t];
        s[12] = KA * r0 + KB2 * u0 + KC * w0 + x[3];
        s[13] = KA * r1 + KB2 * u1 + KC * w1 + x[4];
        s[14] = KA * r2 + KB2 * u2 + KC * w2 + x[5];
    }
    __syncthreads();                                    // B7

    // ---------------------- pairwise distances (no integer division) --------
    #pragma unroll
    for (int it = 0; it < 6; ++it) {
        int idx = it * 256 + tid;
        int k = idx >> 5, pq = idx & 31;
        if (pq < 25) {
            int p = pq / 5, q = pq % 5;
            float dx = uA.geo[720 + p * 3 + 0] - uA.geo[k * 15 + q * 3 + 0];
            float dy = uA.geo[720 + p * 3 + 1] - uA.geo[k * 15 + q * 3 + 1];
            float dz = uA.geo[720 + p * 3 + 2] - uA.geo[k * 15 + q * 3 + 2];
            sD[k * 25 + pq] = sqrtf(dx * dx + dy * dy + dz * dz + 1e-6f);
        }
    }
    __syncthreads();                                    // B8

    // --------- feature compute: Gaussian ladder via multiplicative chain ----
    auto feat_compute = [&](int kt, int fb) {
        if (tid < 192) {
            int pair = tid >> 1, half = tid & 1;
            int k = pair >> 1, pq_lo = pair & 1;
            int pq = kt * 2 + pq_lo;
            bf16x8 ov;
            if (pq < 25) {
                float Dv = sD[k * 25 + pq];
                float t0 = (Dv - 2.0f) * 0.8f;
                float tm = __builtin_fmaf(-(float)(half << 3), DLT, t0);
                tm = fminf(tm, TM_CLAMP);
                float vv = exp2f(-(tm * tm) * L2E);       // exp(-tm^2)
                float s  = exp2f(EXP_2DT * tm) * KC1;     // e^{2*DLT*tm - DLT^2}
                __hip_bfloat16 hb = __float2bfloat16(vv);
                ov[0] = *reinterpret_cast<short*>(&hb);
                #pragma unroll
                for (int mi = 1; mi < 8; ++mi) {
                    vv *= s;
                    s  *= KC2;
                    hb = __float2bfloat16(vv);
                    ov[mi] = *reinterpret_cast<short*>(&hb);
                }
            } else {
                #pragma unroll
                for (int mi = 0; mi < 8; ++mi) ov[mi] = 0;
            }
            *reinterpret_cast<bf16x8*>(
                &sFeat[fb][k * FSTR + pq_lo * 16 + (half << 3)]) = ov;
        }
    };

    feat_compute(0, 0);
    __syncthreads();                                    // B9

    // -------------------------------------------- MFMA GEMM, 13+3 K-steps ---
    f32x4 acc[3][2];
    #pragma unroll
    for (int mt = 0; mt < 3; ++mt)
        #pragma unroll
        for (int nb = 0; nb < 2; ++nb) acc[mt][nb] = (f32x4){0.f, 0.f, 0.f, 0.f};
    const int nt0 = wid * 2;
    const int arow = lane & 15, kg = lane >> 4;

    int cur = 0;
    #pragma unroll 1
    for (int kt = 0; kt < 13; ++kt) {
        const short* wp = Wt + (((size_t)(kt * 8 + nt0) * 16 + arow) * 32 + kg * 8);
        bf16x8 b0 = *reinterpret_cast<const bf16x8*>(wp);
        bf16x8 b1 = *reinterpret_cast<const bf16x8*>(wp + 16 * 32);
        if (kt + 1 < 13) feat_compute(kt + 1, cur ^ 1);
        bf16x8 a0 = *reinterpret_cast<const bf16x8*>(&sFeat[cur][(arow     ) * FSTR + kg * 8]);
        bf16x8 a1 = *reinterpret_cast<const bf16x8*>(&sFeat[cur][(arow + 16) * FSTR + kg * 8]);
        bf16x8 a2 = *reinterpret_cast<const bf16x8*>(&sFeat[cur][(arow + 32) * FSTR + kg * 8]);
        acc[0][0] = __builtin_amdgcn_mfma_f32_16x16x32_bf16(a0, b0, acc[0][0], 0, 0, 0);
        acc[1][0] = __builtin_amdgcn_mfma_f32_16x16x32_bf16(a1, b0, acc[1][0], 0, 0, 0);
        acc[2][0] = __builtin_amdgcn_mfma_f32_16x16x32_bf16(a2, b0, acc[2][0], 0, 0, 0);
        acc[0][1] = __builtin_amdgcn_mfma_f32_16x16x32_bf16(a0, b1, acc[0][1], 0, 0, 0);
        acc[1][1] = __builtin_amdgcn_mfma_f32_16x16x32_bf16(a1, b1, acc[1][1], 0, 0, 0);
        acc[2][1] = __builtin_amdgcn_mfma_f32_16x16x32_bf16(a2, b1, acc[2][1], 0, 0, 0);
        if (kt + 1 < 13) { __syncthreads(); cur ^= 1; }   // publish next buffer
    }

    // pe one-hot K-steps (u64-shift one-hot, validated in pf14; no barriers)
    int dc0 = sDcode[arow], dc1 = sDcode[arow + 16], dc2 = sDcode[arow + 32];
    #pragma unroll 1
    for (int kp = 0; kp < 3; ++kp) {
        int base = kp * 32 + kg * 8;
        union OneHot { unsigned long long u[2]; bf16x8 v; } oh0, oh1, oh2;
        unsigned int i0 = (unsigned)(dc0 - base);
        unsigned int i1 = (unsigned)(dc1 - base);
        unsigned int i2 = (unsigned)(dc2 - base);
        oh0.u[0] = (i0 < 4) ? (0x3F80ULL << (i0 * 16)) : 0ULL;
        oh0.u[1] = (i0 - 4 < 4) ? (0x3F80ULL << ((i0 - 4) * 16)) : 0ULL;
        oh1.u[0] = (i1 < 4) ? (0x3F80ULL << (i1 * 16)) : 0ULL;
        oh1.u[1] = (i1 - 4 < 4) ? (0x3F80ULL << ((i1 - 4) * 16)) : 0ULL;
        oh2.u[0] = (i2 < 4) ? (0x3F80ULL << (i2 * 16)) : 0ULL;
        oh2.u[1] = (i2 - 4 < 4) ? (0x3F80ULL << ((i2 - 4) * 16)) : 0ULL;
        const short* wp = Wt + (((size_t)((13 + kp) * 8 + nt0) * 16 + arow) * 32 + kg * 8);
        bf16x8 b0 = *reinterpret_cast<const bf16x8*>(wp);
        bf16x8 b1 = *reinterpret_cast<const bf16x8*>(wp + 16 * 32);
        acc[0][0] = __builtin_amdgcn_mfma_f32_16x16x32_bf16(oh0.v, b0, acc[0][0], 0, 0, 0);
        acc[1][0] = __builtin_amdgcn_mfma_f32_16x16x32_bf16(oh1.v, b0, acc[1][0], 0, 0, 0);
        acc[2][0] = __builtin_amdgcn_mfma_f32_16x16x32_bf16(oh2.v, b0, acc[2][0], 0, 0, 0);
        acc[0][1] = __builtin_amdgcn_mfma_f32_16x16x32_bf16(oh0.v, b1, acc[0][1], 0, 0, 0);
        acc[1][1] = __builtin_amdgcn_mfma_f32_16x16x32_bf16(oh1.v, b1, acc[1][1], 0, 0, 0);
        acc[2][1] = __builtin_amdgcn_mfma_f32_16x16x32_bf16(oh2.v, b1, acc[2][1], 0, 0, 0);
    }

    // --------------------------- layernorm: cross-wave partials via LDS -----
    // C/D layout: col = (nt0+nb)*16 + arow, edge e = mt*16 + kg*4 + r
    #pragma unroll
    for (int mt = 0; mt < 3; ++mt)
        #pragma unroll
        for (int r = 0; r < 4; ++r) {
            float s = acc[mt][0][r] + acc[mt][1][r];
            float ss = acc[mt][0][r] * acc[mt][0][r]
                     + acc[mt][1][r] * acc[mt][1][r];
            s  += __shfl_xor(s, 1, 64);  ss += __shfl_xor(ss, 1, 64);
            s  += __shfl_xor(s, 2, 64);  ss += __shfl_xor(ss, 2, 64);
            s  += __shfl_xor(s, 4, 64);  ss += __shfl_xor(ss, 4, 64);
            s  += __shfl_xor(s, 8, 64);  ss += __shfl_xor(ss, 8, 64);
            if (arow == 0) {
                int e = mt * 16 + kg * 4 + r;
                sPartS[e][wid] = s;
                sPartSS[e][wid] = ss;
            }
        }
    __syncthreads();                                    // B10
    if (tid < KK) {
        float s = sPartS[tid][0] + sPartS[tid][1] + sPartS[tid][2] + sPartS[tid][3];
        float ss = sPartSS[tid][0] + sPartSS[tid][1] + sPartSS[tid][2] + sPartSS[tid][3];
        float mean = s * (1.0f / 128.0f);
        float var = ss * (1.0f / 128.0f) - mean * mean;
        sMean[tid] = mean;
        sInv[tid] = 1.0f / sqrtf(var + 1e-5f);
    }
    __syncthreads();                                    // B11

    // --------------------------------- normalize + store from registers -----
    const int col0 = nt0 * 16 + arow, col1 = col0 + 16;
    const float g0 = sGB[col0 * 2], be0 = sGB[col0 * 2 + 1];
    const float g1 = sGB[col1 * 2], be1 = sGB[col1 * 2 + 1];
    float* outR = outEdge + (size_t)row * KK * HH;
    #pragma unroll
    for (int mt = 0; mt < 3; ++mt)
        #pragma unroll
        for (int r = 0; r < 4; ++r) {
            int e = mt * 16 + kg * 4 + r;
            float mean = sMean[e], inv = sInv[e];
            outR[(size_t)e * HH + col0] = (acc[mt][0][r] - mean) * inv * g0 + be0;
            outR[(size_t)e * HH + col1] = (acc[mt][1][r] - mean) * inv * g1 + be1;
        }
}

// ---------------------------------------------------------------- launch ----
extern "C" void kernel_launch(void* const* d_in, const int* in_sizes, int n_in,
                              void* d_out, int out_size, void* d_ws, size_t ws_size,
                              hipStream_t stream) {
    const float* X     = (const float*)d_in[0];
    const float* mask  = (const float*)d_in[1];
    const int*   Ridx  = (const int*)d_in[2];
    const int*   chain = (const int*)d_in[3];
    const float* Wpos  = (const float*)d_in[4];
    const float* bpos  = (const float*)d_in[5];
    const float* Wedge = (const float*)d_in[6];
    const float* gamma = (const float*)d_in[7];
    const float* beta  = (const float*)d_in[8];

    float* outBase = (float*)d_out;
    float* outIdx  = outBase;                          // (B,L,K) f32
    float* outEdge = outBase + (size_t)BB * LL * KK;   // (B,L,K,H) f32

    short*  Wt  = (short*)d_ws;                                    // 128 KiB
    float4* caq = (float4*)((char*)d_ws + 16 * 8 * 16 * 32 * 2);   // 128 KiB

    hipLaunchKernelGGL(pf22_prep_w, dim3(256), dim3(256), 0, stream,
                       Wedge, Wpos, bpos, Wt);
    hipLaunchKernelGGL(pf22_prep_ca, dim3((BB * LL + 255) / 256), dim3(256), 0,
                       stream, X, mask, caq);
    hipLaunchKernelGGL(pf22_main, dim3(BB * LL), dim3(256), 0, stream,
                       X, Ridx, chain, gamma, beta, Wt, caq, outIdx, outEdge);
}